// Round 3
// baseline (455.884 us; speedup 1.0000x reference)
//
#include <hip/hip_runtime.h>
#include <hip/hip_bf16.h>
#include <cstdint>

#define BB 8
#define SS 2048
#define DD 1024
#define HH 1024

typedef __bf16 bf16x8 __attribute__((ext_vector_type(8)));
typedef float f32x4 __attribute__((ext_vector_type(4)));

__device__ __forceinline__ float bf2f(uint16_t h) {
  union { uint32_t u; float f; } v; v.u = ((uint32_t)h) << 16; return v.f;
}
__device__ __forceinline__ uint16_t f2bf(float f) {
  union { float f; uint32_t u; } v; v.f = f;
  uint32_t u = v.u;
  return (uint16_t)((u + 0x7FFFu + ((u >> 16) & 1u)) >> 16);
}

// fp32 -> bf16 (RNE), vectorized 8 elems/thread, grid-stride. n % 8 == 0.
__global__ void cvt_f32_bf16(const float* __restrict__ src,
                             uint16_t* __restrict__ dst, int n) {
  int i = (blockIdx.x * blockDim.x + threadIdx.x) * 8;
  const int stride = gridDim.x * blockDim.x * 8;
  for (; i < n; i += stride) {
    float4 f0 = *(const float4*)(src + i);
    float4 f1 = *(const float4*)(src + i + 4);
    alignas(16) uint16_t o[8];
    o[0] = f2bf(f0.x); o[1] = f2bf(f0.y); o[2] = f2bf(f0.z); o[3] = f2bf(f0.w);
    o[4] = f2bf(f1.x); o[5] = f2bf(f1.y); o[6] = f2bf(f1.z); o[7] = f2bf(f1.w);
    *(uint4*)(dst + i) = *(const uint4*)o;
  }
}

// three same-size fp32->bf16 converts in one dispatch (blockIdx.y selects)
__global__ void cvt3_f32_bf16(const float* __restrict__ s0, const float* __restrict__ s1,
                              const float* __restrict__ s2, uint16_t* __restrict__ d0,
                              uint16_t* __restrict__ d1, uint16_t* __restrict__ d2, int n) {
  const float* src = (blockIdx.y == 0) ? s0 : (blockIdx.y == 1) ? s1 : s2;
  uint16_t* dst = (blockIdx.y == 0) ? d0 : (blockIdx.y == 1) ? d1 : d2;
  int i = (blockIdx.x * blockDim.x + threadIdx.x) * 8;
  const int stride = gridDim.x * blockDim.x * 8;
  for (; i < n; i += stride) {
    float4 f0 = *(const float4*)(src + i);
    float4 f1 = *(const float4*)(src + i + 4);
    alignas(16) uint16_t o[8];
    o[0] = f2bf(f0.x); o[1] = f2bf(f0.y); o[2] = f2bf(f0.z); o[3] = f2bf(f0.w);
    o[4] = f2bf(f1.x); o[5] = f2bf(f1.y); o[6] = f2bf(f1.z); o[7] = f2bf(f1.w);
    *(uint4*)(dst + i) = *(const uint4*)o;
  }
}

// NT GEMM: C[m][n] = sum_k A[m][k] * B[n][k]  (both operands K-contiguous, bf16)
// MODE 0: QK projection. M=16384,N=1024,K=1024. +bias(fp32). C row-major bf16.
// MODE 1: V projection, transposed epilogue -> Vt[b][h][s]. +bias.
// MODE 2: scores = Q Kt / 32 per batch (grid.z). skip tiles tn>tm (causal).
// MODE 3: PV per batch (grid.z). A=P (ld 2048), B=Vt (ld 2048). kmax causal.
//         Output is fp32 (harness reads d_out as float32 per reference dtype).
template <int MODE>
__launch_bounds__(256, 2)
__global__ void gemm_bt(const uint16_t* __restrict__ Aroot,
                        const uint16_t* __restrict__ Broot,
                        const float* __restrict__ bias,
                        void* __restrict__ Croot) {
  constexpr int K   = (MODE == 3) ? 2048 : 1024;
  constexpr int LDA = (MODE == 3) ? 2048 : 1024;
  constexpr int LDB = (MODE == 3) ? 2048 : 1024;
  constexpr int LDC = (MODE == 2) ? 2048 : 1024;

  const int tm = blockIdx.x, tn = blockIdx.y;
  if constexpr (MODE == 2) { if (tn > tm) return; }

  const uint16_t* A = Aroot;
  const uint16_t* Bp = Broot;
  uint16_t* C16 = (uint16_t*)Croot;
  float*    C32 = (float*)Croot;
  if constexpr (MODE == 2) {
    size_t z = blockIdx.z;
    A  += z * (size_t)(SS * DD);
    Bp += z * (size_t)(SS * DD);
    C16 += z * (size_t)SS * (size_t)SS;
  }
  if constexpr (MODE == 3) {
    size_t z = blockIdx.z;
    A  += z * (size_t)SS * (size_t)SS;
    Bp += z * (size_t)(HH * SS);
    C32 += z * (size_t)(SS * HH);
  }

  const int m0 = tm * 128, n0 = tn * 128;
  int kmax = K;
  if constexpr (MODE == 3) {
    kmax = (tm + 1) * 128;
    if (kmax > K) kmax = K;
  }

  __shared__ uint16_t As[128 * 32];
  __shared__ uint16_t Bs[128 * 32];

  const int tid  = threadIdx.x;
  const int lane = tid & 63;
  const int wv   = tid >> 6;
  const int wm   = (wv & 1) * 64;   // wave's m offset within 128-tile
  const int wn   = (wv >> 1) * 64;  // wave's n offset

  f32x4 acc[4][4];
#pragma unroll
  for (int i = 0; i < 4; i++)
#pragma unroll
    for (int j = 0; j < 4; j++)
#pragma unroll
      for (int e = 0; e < 4; e++) acc[i][j][e] = 0.f;

  // staging: 256 threads, each moves 2x16B of A-tile and 2x16B of B-tile
  const int sr = tid >> 2;        // 0..63
  const int sc = (tid & 3) * 8;   // 0,8,16,24 (bf16 elements)

  // fragment indices (A and B operands share the same lane mapping)
  const int fr = lane & 15;
  const int fk = (lane >> 4) * 8;

  for (int k0 = 0; k0 < kmax; k0 += 32) {
    uint4 a0 = *(const uint4*)(A + (size_t)(m0 + sr) * LDA + k0 + sc);
    uint4 a1 = *(const uint4*)(A + (size_t)(m0 + sr + 64) * LDA + k0 + sc);
    uint4 b0 = *(const uint4*)(Bp + (size_t)(n0 + sr) * LDB + k0 + sc);
    uint4 b1 = *(const uint4*)(Bp + (size_t)(n0 + sr + 64) * LDB + k0 + sc);
    __syncthreads();
    *(uint4*)&As[sr * 32 + sc] = a0;
    *(uint4*)&As[(sr + 64) * 32 + sc] = a1;
    *(uint4*)&Bs[sr * 32 + sc] = b0;
    *(uint4*)&Bs[(sr + 64) * 32 + sc] = b1;
    __syncthreads();

    bf16x8 af[4], bfr[4];
#pragma unroll
    for (int i = 0; i < 4; i++) {
      uint4 t = *(const uint4*)&As[(wm + i * 16 + fr) * 32 + fk];
      af[i] = __builtin_bit_cast(bf16x8, t);
    }
#pragma unroll
    for (int j = 0; j < 4; j++) {
      uint4 t = *(const uint4*)&Bs[(wn + j * 16 + fr) * 32 + fk];
      bfr[j] = __builtin_bit_cast(bf16x8, t);
    }
#pragma unroll
    for (int i = 0; i < 4; i++)
#pragma unroll
      for (int j = 0; j < 4; j++)
        acc[i][j] = __builtin_amdgcn_mfma_f32_16x16x32_bf16(af[i], bfr[j], acc[i][j], 0, 0, 0);
  }

  // epilogue: C/D mapping col = lane&15, row = (lane>>4)*4 + e  [verified m89/m91]
  const int cr = (lane >> 4) * 4;
  const int cc = lane & 15;
#pragma unroll
  for (int i = 0; i < 4; i++) {
#pragma unroll
    for (int j = 0; j < 4; j++) {
      const int row0 = m0 + wm + i * 16 + cr;
      const int col  = n0 + wn + j * 16 + cc;
      float badd = 0.f;
      if constexpr (MODE == 0 || MODE == 1) badd = bias[col];
#pragma unroll
      for (int e = 0; e < 4; e++) {
        float x = acc[i][j][e] + badd;
        if constexpr (MODE == 2) x *= 0.03125f;  // 1/sqrt(H) = 1/32
        const int r = row0 + e;
        if constexpr (MODE == 1) {
          const int bz = r >> 11;
          const int s  = r & (SS - 1);
          C16[(size_t)bz * (HH * SS) + (size_t)col * SS + s] = f2bf(x);
        } else if constexpr (MODE == 3) {
          C32[(size_t)r * LDC + col] = x;          // fp32 final output
        } else {
          C16[(size_t)r * LDC + col] = f2bf(x);
        }
      }
    }
  }
}

// one block (256 threads) per row; each thread owns 8 contiguous columns.
// Reads S row (bf16), writes normalized P in-place, zero-fills j>i.
__launch_bounds__(256)
__global__ void softmax_causal(uint16_t* __restrict__ Sb) {
  const int rgl = blockIdx.x;          // 0..B*S-1
  const int b = rgl >> 11;
  const int i = rgl & (SS - 1);
  uint16_t* row = Sb + (size_t)b * SS * SS + (size_t)i * SS;
  const int t = threadIdx.x;
  const int base = t * 8;

  uint4 u = *(const uint4*)(row + base);
  const uint16_t* hs = (const uint16_t*)&u;
  float x[8];
  float lmax = -3.0e38f;
#pragma unroll
  for (int e = 0; e < 8; e++) {
    float f = bf2f(hs[e]);
    x[e] = (base + e <= i) ? f : -3.0e38f;
    lmax = fmaxf(lmax, x[e]);
  }
#pragma unroll
  for (int off = 32; off > 0; off >>= 1)
    lmax = fmaxf(lmax, __shfl_down(lmax, off));

  __shared__ float red[8];
  if ((t & 63) == 0) red[t >> 6] = lmax;
  __syncthreads();
  const float m = fmaxf(fmaxf(red[0], red[1]), fmaxf(red[2], red[3]));

  float lsum = 0.f;
#pragma unroll
  for (int e = 0; e < 8; e++) {
    float p = (base + e <= i) ? __expf(x[e] - m) : 0.f;
    x[e] = p;
    lsum += p;
  }
#pragma unroll
  for (int off = 32; off > 0; off >>= 1) lsum += __shfl_down(lsum, off);
  if ((t & 63) == 0) red[4 + (t >> 6)] = lsum;
  __syncthreads();
  const float inv = 1.f / (red[4] + red[5] + red[6] + red[7]);

  alignas(16) uint16_t o[8];
#pragma unroll
  for (int e = 0; e < 8; e++) o[e] = f2bf(x[e] * inv);
  *(uint4*)(row + base) = *(const uint4*)o;
}

extern "C" void kernel_launch(void* const* d_in, const int* in_sizes, int n_in,
                              void* d_out, int out_size, void* d_ws, size_t ws_size,
                              hipStream_t stream) {
  // Inputs fp32 per the reference; output fp32 (reference output dtype).
  const float* x  = (const float*)d_in[0];
  const float* Wq = (const float*)d_in[1];
  const float* bq = (const float*)d_in[2];
  const float* Wk = (const float*)d_in[3];
  const float* bk = (const float*)d_in[4];
  const float* Wv = (const float*)d_in[5];
  const float* bv = (const float*)d_in[6];

  uint16_t* ws = (uint16_t*)d_ws;
  const size_t QKV = (size_t)BB * SS * HH;  // 16,777,216 elems = 32 MB bf16
  uint16_t* Q  = ws;
  uint16_t* Kp = ws + QKV;
  uint16_t* Vt = ws + 2 * QKV;
  uint16_t* Sb = ws + 3 * QKV;              // 8*2048*2048 bf16 = 64 MB
  // xb + converted weights alias the Sb region (dead before MODE 2 writes Sb)
  uint16_t* xb  = Sb;                       // 16,777,216 elems
  uint16_t* Wqb = Sb + QKV;                 // 1,048,576 elems each
  uint16_t* Wkb = Wqb + (size_t)HH * DD;
  uint16_t* Wvb = Wkb + (size_t)HH * DD;

  dim3 blk(256);
  const int nx = BB * SS * DD;              // 16,777,216
  const int nw = HH * DD;                   // 1,048,576
  cvt_f32_bf16<<<dim3(nx / 2048), blk, 0, stream>>>(x, xb, nx);
  cvt3_f32_bf16<<<dim3(nw / 2048, 3), blk, 0, stream>>>(Wq, Wk, Wv, Wqb, Wkb, Wvb, nw);

  dim3 gproj(BB * SS / 128, HH / 128);      // (128, 8)
  gemm_bt<0><<<gproj, blk, 0, stream>>>(xb, Wqb, bq, Q);
  gemm_bt<0><<<gproj, blk, 0, stream>>>(xb, Wkb, bk, Kp);
  gemm_bt<1><<<gproj, blk, 0, stream>>>(xb, Wvb, bv, Vt);
  gemm_bt<2><<<dim3(SS / 128, SS / 128, BB), blk, 0, stream>>>(Q, Kp, nullptr, Sb);
  softmax_causal<<<dim3(BB * SS), blk, 0, stream>>>(Sb);
  gemm_bt<3><<<dim3(SS / 128, HH / 128, BB), blk, 0, stream>>>(Sb, Vt, nullptr, d_out);
}

// Round 4
// 445.489 us; speedup vs baseline: 1.0233x; 1.0233x over previous
//
#include <hip/hip_runtime.h>
#include <hip/hip_bf16.h>
#include <cstdint>

#define BB 8
#define SS 2048
#define DD 1024
#define HH 1024

typedef __bf16 bf16x8 __attribute__((ext_vector_type(8)));
typedef float f32x4 __attribute__((ext_vector_type(4)));

// address-space casts for global_load_lds (direct global->LDS DMA)
#define AS1C(p) ((const __attribute__((address_space(1))) void*)(p))
#define AS3(p)  ((__attribute__((address_space(3))) void*)(p))

__device__ __forceinline__ float bf2f(uint16_t h) {
  union { uint32_t u; float f; } v; v.u = ((uint32_t)h) << 16; return v.f;
}
__device__ __forceinline__ uint16_t f2bf(float f) {
  union { float f; uint32_t u; } v; v.f = f;
  uint32_t u = v.u;
  return (uint16_t)((u + 0x7FFFu + ((u >> 16) & 1u)) >> 16);
}

// fp32 -> bf16 (RNE), vectorized 8 elems/thread, grid-stride. n % 8 == 0.
__global__ void cvt_f32_bf16(const float* __restrict__ src,
                             uint16_t* __restrict__ dst, int n) {
  int i = (blockIdx.x * blockDim.x + threadIdx.x) * 8;
  const int stride = gridDim.x * blockDim.x * 8;
  for (; i < n; i += stride) {
    float4 f0 = *(const float4*)(src + i);
    float4 f1 = *(const float4*)(src + i + 4);
    alignas(16) uint16_t o[8];
    o[0] = f2bf(f0.x); o[1] = f2bf(f0.y); o[2] = f2bf(f0.z); o[3] = f2bf(f0.w);
    o[4] = f2bf(f1.x); o[5] = f2bf(f1.y); o[6] = f2bf(f1.z); o[7] = f2bf(f1.w);
    *(uint4*)(dst + i) = *(const uint4*)o;
  }
}

// three same-size fp32->bf16 converts in one dispatch (blockIdx.y selects)
__global__ void cvt3_f32_bf16(const float* __restrict__ s0, const float* __restrict__ s1,
                              const float* __restrict__ s2, uint16_t* __restrict__ d0,
                              uint16_t* __restrict__ d1, uint16_t* __restrict__ d2, int n) {
  const float* src = (blockIdx.y == 0) ? s0 : (blockIdx.y == 1) ? s1 : s2;
  uint16_t* dst = (blockIdx.y == 0) ? d0 : (blockIdx.y == 1) ? d1 : d2;
  int i = (blockIdx.x * blockDim.x + threadIdx.x) * 8;
  const int stride = gridDim.x * blockDim.x * 8;
  for (; i < n; i += stride) {
    float4 f0 = *(const float4*)(src + i);
    float4 f1 = *(const float4*)(src + i + 4);
    alignas(16) uint16_t o[8];
    o[0] = f2bf(f0.x); o[1] = f2bf(f0.y); o[2] = f2bf(f0.z); o[3] = f2bf(f0.w);
    o[4] = f2bf(f1.x); o[5] = f2bf(f1.y); o[6] = f2bf(f1.z); o[7] = f2bf(f1.w);
    *(uint4*)(dst + i) = *(const uint4*)o;
  }
}

// NT GEMM: C[m][n] = sum_k A[m][k] * B[n][k]  (both operands K-contiguous, bf16)
// Staging via global_load_lds width=16 (m97 pattern): per K-step each wave
// issues 2 A-chunks + 2 B-chunks; one chunk = 64 lanes x 16B = 16 rows x 64B,
// LDS dest is wave-uniform base + lane*16 which matches the unpadded
// row-major As/Bs layout exactly (m104/m108 caveat respected).
// MODE 0: QK projection. +bias(fp32). C row-major bf16.
// MODE 1: V projection, transposed epilogue -> Vt[b][h][s]. +bias.
// MODE 2: scores = Q Kt / 32 per batch (grid.z). skip tiles tn>tm (causal).
// MODE 3: PV per batch (grid.z). kmax causal. fp32 output.
template <int MODE>
__launch_bounds__(256, 2)
__global__ void gemm_bt(const uint16_t* __restrict__ Aroot,
                        const uint16_t* __restrict__ Broot,
                        const float* __restrict__ bias,
                        void* __restrict__ Croot) {
  constexpr int K   = (MODE == 3) ? 2048 : 1024;
  constexpr int LDA = (MODE == 3) ? 2048 : 1024;
  constexpr int LDB = (MODE == 3) ? 2048 : 1024;
  constexpr int LDC = (MODE == 2) ? 2048 : 1024;

  const int tm = blockIdx.x, tn = blockIdx.y;
  if constexpr (MODE == 2) { if (tn > tm) return; }

  const uint16_t* A = Aroot;
  const uint16_t* Bp = Broot;
  uint16_t* C16 = (uint16_t*)Croot;
  float*    C32 = (float*)Croot;
  if constexpr (MODE == 2) {
    size_t z = blockIdx.z;
    A  += z * (size_t)(SS * DD);
    Bp += z * (size_t)(SS * DD);
    C16 += z * (size_t)SS * (size_t)SS;
  }
  if constexpr (MODE == 3) {
    size_t z = blockIdx.z;
    A  += z * (size_t)SS * (size_t)SS;
    Bp += z * (size_t)(HH * SS);
    C32 += z * (size_t)(SS * HH);
  }

  const int m0 = tm * 128, n0 = tn * 128;
  int kmax = K;
  if constexpr (MODE == 3) {
    kmax = (tm + 1) * 128;
    if (kmax > K) kmax = K;
  }

  __shared__ uint16_t As[128 * 32];
  __shared__ uint16_t Bs[128 * 32];

  const int tid  = threadIdx.x;
  const int lane = tid & 63;
  const int wv   = tid >> 6;
  const int wm   = (wv & 1) * 64;   // wave's m offset within 128-tile
  const int wn   = (wv >> 1) * 64;  // wave's n offset

  f32x4 acc[4][4];
#pragma unroll
  for (int i = 0; i < 4; i++)
#pragma unroll
    for (int j = 0; j < 4; j++)
#pragma unroll
      for (int e = 0; e < 4; e++) acc[i][j][e] = 0.f;

  // global_load_lds lane mapping within a 16-row chunk:
  // lane l -> row l>>2, byte col (l&3)*16  == elements (l&3)*8
  const int lrow = lane >> 2;
  const int lcol = (lane & 3) * 8;
  const int r0   = wv * 32;         // this wave's 32-row slab (2 chunks)

  // per-wave global base pointers (row within tile = r0 + lrow)
  const uint16_t* gA = A + (size_t)(m0 + r0 + lrow) * LDA + lcol;
  const uint16_t* gB = Bp + (size_t)(n0 + r0 + lrow) * LDB + lcol;

  // fragment indices (A and B operands share the same lane mapping)
  const int fr = lane & 15;
  const int fk = (lane >> 4) * 8;

  for (int k0 = 0; k0 < kmax; k0 += 32) {
    __syncthreads();  // previous iter's ds_reads done before overwrite
    __builtin_amdgcn_global_load_lds(AS1C(gA + k0), AS3(&As[r0 * 32]), 16, 0, 0);
    __builtin_amdgcn_global_load_lds(AS1C(gA + k0 + 16 * LDA), AS3(&As[(r0 + 16) * 32]), 16, 0, 0);
    __builtin_amdgcn_global_load_lds(AS1C(gB + k0), AS3(&Bs[r0 * 32]), 16, 0, 0);
    __builtin_amdgcn_global_load_lds(AS1C(gB + k0 + 16 * LDB), AS3(&Bs[(r0 + 16) * 32]), 16, 0, 0);
    __syncthreads();  // drains vmcnt(0): tiles staged

    bf16x8 af[4], bfr[4];
#pragma unroll
    for (int i = 0; i < 4; i++) {
      uint4 t = *(const uint4*)&As[(wm + i * 16 + fr) * 32 + fk];
      af[i] = __builtin_bit_cast(bf16x8, t);
    }
#pragma unroll
    for (int j = 0; j < 4; j++) {
      uint4 t = *(const uint4*)&Bs[(wn + j * 16 + fr) * 32 + fk];
      bfr[j] = __builtin_bit_cast(bf16x8, t);
    }
#pragma unroll
    for (int i = 0; i < 4; i++)
#pragma unroll
      for (int j = 0; j < 4; j++)
        acc[i][j] = __builtin_amdgcn_mfma_f32_16x16x32_bf16(af[i], bfr[j], acc[i][j], 0, 0, 0);
  }

  // epilogue: C/D mapping col = lane&15, row = (lane>>4)*4 + e  [verified m89/m91]
  const int cr = (lane >> 4) * 4;
  const int cc = lane & 15;
#pragma unroll
  for (int i = 0; i < 4; i++) {
#pragma unroll
    for (int j = 0; j < 4; j++) {
      const int row0 = m0 + wm + i * 16 + cr;
      const int col  = n0 + wn + j * 16 + cc;
      float badd = 0.f;
      if constexpr (MODE == 0 || MODE == 1) badd = bias[col];
#pragma unroll
      for (int e = 0; e < 4; e++) {
        float x = acc[i][j][e] + badd;
        if constexpr (MODE == 2) x *= 0.03125f;  // 1/sqrt(H) = 1/32
        const int r = row0 + e;
        if constexpr (MODE == 1) {
          const int bz = r >> 11;
          const int s  = r & (SS - 1);
          C16[(size_t)bz * (HH * SS) + (size_t)col * SS + s] = f2bf(x);
        } else if constexpr (MODE == 3) {
          C32[(size_t)r * LDC + col] = x;          // fp32 final output
        } else {
          C16[(size_t)r * LDC + col] = f2bf(x);
        }
      }
    }
  }
}

// one block (256 threads) per row; each thread owns 8 contiguous columns.
// Reads S row (bf16), writes normalized P in-place, zero-fills j>i.
__launch_bounds__(256)
__global__ void softmax_causal(uint16_t* __restrict__ Sb) {
  const int rgl = blockIdx.x;          // 0..B*S-1
  const int b = rgl >> 11;
  const int i = rgl & (SS - 1);
  uint16_t* row = Sb + (size_t)b * SS * SS + (size_t)i * SS;
  const int t = threadIdx.x;
  const int base = t * 8;

  uint4 u = *(const uint4*)(row + base);
  const uint16_t* hs = (const uint16_t*)&u;
  float x[8];
  float lmax = -3.0e38f;
#pragma unroll
  for (int e = 0; e < 8; e++) {
    float f = bf2f(hs[e]);
    x[e] = (base + e <= i) ? f : -3.0e38f;
    lmax = fmaxf(lmax, x[e]);
  }
#pragma unroll
  for (int off = 32; off > 0; off >>= 1)
    lmax = fmaxf(lmax, __shfl_down(lmax, off));

  __shared__ float red[8];
  if ((t & 63) == 0) red[t >> 6] = lmax;
  __syncthreads();
  const float m = fmaxf(fmaxf(red[0], red[1]), fmaxf(red[2], red[3]));

  float lsum = 0.f;
#pragma unroll
  for (int e = 0; e < 8; e++) {
    float p = (base + e <= i) ? __expf(x[e] - m) : 0.f;
    x[e] = p;
    lsum += p;
  }
#pragma unroll
  for (int off = 32; off > 0; off >>= 1) lsum += __shfl_down(lsum, off);
  if ((t & 63) == 0) red[4 + (t >> 6)] = lsum;
  __syncthreads();
  const float inv = 1.f / (red[4] + red[5] + red[6] + red[7]);

  alignas(16) uint16_t o[8];
#pragma unroll
  for (int e = 0; e < 8; e++) o[e] = f2bf(x[e] * inv);
  *(uint4*)(row + base) = *(const uint4*)o;
}

extern "C" void kernel_launch(void* const* d_in, const int* in_sizes, int n_in,
                              void* d_out, int out_size, void* d_ws, size_t ws_size,
                              hipStream_t stream) {
  // Inputs fp32 per the reference; output fp32 (reference output dtype).
  const float* x  = (const float*)d_in[0];
  const float* Wq = (const float*)d_in[1];
  const float* bq = (const float*)d_in[2];
  const float* Wk = (const float*)d_in[3];
  const float* bk = (const float*)d_in[4];
  const float* Wv = (const float*)d_in[5];
  const float* bv = (const float*)d_in[6];

  uint16_t* ws = (uint16_t*)d_ws;
  const size_t QKV = (size_t)BB * SS * HH;  // 16,777,216 elems = 32 MB bf16
  uint16_t* Q  = ws;
  uint16_t* Kp = ws + QKV;
  uint16_t* Vt = ws + 2 * QKV;
  uint16_t* Sb = ws + 3 * QKV;              // 8*2048*2048 bf16 = 64 MB
  // xb + converted weights alias the Sb region (dead before MODE 2 writes Sb)
  uint16_t* xb  = Sb;                       // 16,777,216 elems
  uint16_t* Wqb = Sb + QKV;                 // 1,048,576 elems each
  uint16_t* Wkb = Wqb + (size_t)HH * DD;
  uint16_t* Wvb = Wkb + (size_t)HH * DD;

  dim3 blk(256);
  const int nx = BB * SS * DD;              // 16,777,216
  const int nw = HH * DD;                   // 1,048,576
  cvt_f32_bf16<<<dim3(nx / 2048), blk, 0, stream>>>(x, xb, nx);
  cvt3_f32_bf16<<<dim3(nw / 2048, 3), blk, 0, stream>>>(Wq, Wk, Wv, Wqb, Wkb, Wvb, nw);

  dim3 gproj(BB * SS / 128, HH / 128);      // (128, 8)
  gemm_bt<0><<<gproj, blk, 0, stream>>>(xb, Wqb, bq, Q);
  gemm_bt<0><<<gproj, blk, 0, stream>>>(xb, Wkb, bk, Kp);
  gemm_bt<1><<<gproj, blk, 0, stream>>>(xb, Wvb, bv, Vt);
  gemm_bt<2><<<dim3(SS / 128, SS / 128, BB), blk, 0, stream>>>(Q, Kp, nullptr, Sb);
  softmax_causal<<<dim3(BB * SS), blk, 0, stream>>>(Sb);
  gemm_bt<3><<<dim3(SS / 128, HH / 128, BB), blk, 0, stream>>>(Sb, Vt, nullptr, d_out);
}

// Round 5
// 434.514 us; speedup vs baseline: 1.0492x; 1.0253x over previous
//
#include <hip/hip_runtime.h>
#include <hip/hip_bf16.h>
#include <cstdint>

#define BB 8
#define SS 2048
#define DD 1024
#define HH 1024

typedef __bf16 bf16x8 __attribute__((ext_vector_type(8)));
typedef float f32x4 __attribute__((ext_vector_type(4)));

// address-space casts for global_load_lds (direct global->LDS DMA)
#define AS1C(p) ((const __attribute__((address_space(1))) void*)(p))
#define AS3(p)  ((__attribute__((address_space(3))) void*)(p))

__device__ __forceinline__ float bf2f(uint16_t h) {
  union { uint32_t u; float f; } v; v.u = ((uint32_t)h) << 16; return v.f;
}
__device__ __forceinline__ uint16_t f2bf(float f) {
  union { float f; uint32_t u; } v; v.f = f;
  uint32_t u = v.u;
  return (uint16_t)((u + 0x7FFFu + ((u >> 16) & 1u)) >> 16);
}

// fp32 -> bf16 (RNE), vectorized 8 elems/thread, grid-stride. n % 8 == 0.
__global__ void cvt_f32_bf16(const float* __restrict__ src,
                             uint16_t* __restrict__ dst, int n) {
  int i = (blockIdx.x * blockDim.x + threadIdx.x) * 8;
  const int stride = gridDim.x * blockDim.x * 8;
  for (; i < n; i += stride) {
    float4 f0 = *(const float4*)(src + i);
    float4 f1 = *(const float4*)(src + i + 4);
    alignas(16) uint16_t o[8];
    o[0] = f2bf(f0.x); o[1] = f2bf(f0.y); o[2] = f2bf(f0.z); o[3] = f2bf(f0.w);
    o[4] = f2bf(f1.x); o[5] = f2bf(f1.y); o[6] = f2bf(f1.z); o[7] = f2bf(f1.w);
    *(uint4*)(dst + i) = *(const uint4*)o;
  }
}

// three same-size fp32->bf16 converts in one dispatch (blockIdx.y selects)
__global__ void cvt3_f32_bf16(const float* __restrict__ s0, const float* __restrict__ s1,
                              const float* __restrict__ s2, uint16_t* __restrict__ d0,
                              uint16_t* __restrict__ d1, uint16_t* __restrict__ d2, int n) {
  const float* src = (blockIdx.y == 0) ? s0 : (blockIdx.y == 1) ? s1 : s2;
  uint16_t* dst = (blockIdx.y == 0) ? d0 : (blockIdx.y == 1) ? d1 : d2;
  int i = (blockIdx.x * blockDim.x + threadIdx.x) * 8;
  const int stride = gridDim.x * blockDim.x * 8;
  for (; i < n; i += stride) {
    float4 f0 = *(const float4*)(src + i);
    float4 f1 = *(const float4*)(src + i + 4);
    alignas(16) uint16_t o[8];
    o[0] = f2bf(f0.x); o[1] = f2bf(f0.y); o[2] = f2bf(f0.z); o[3] = f2bf(f0.w);
    o[4] = f2bf(f1.x); o[5] = f2bf(f1.y); o[6] = f2bf(f1.z); o[7] = f2bf(f1.w);
    *(uint4*)(dst + i) = *(const uint4*)o;
  }
}

// NT GEMM: C[m][n] = sum_k A[m][k] * B[n][k]  (bf16, K-contiguous operands)
// K-loop: BK=64 as two 32-wide LDS buffers (unroll x2) -> 2 barriers per
// 64 K-elems, 32 MFMA per vmcnt drain. Staging via global_load_lds w=16.
// MODE 0: merged QKV projection. B = [Wq;Wk;Wv] (3072x1024). Epilogue picks
//         Q / K / Vt(transposed) + bias by n0>>10 (block-uniform).
// MODE 2: scores = Q Kt / 32 per batch (grid.z). skip tiles tn>tm (causal).
// MODE 3: PV per batch (grid.z). kmax causal. fp32 output.
template <int MODE>
__launch_bounds__(256, 2)
__global__ void gemm_bt(const uint16_t* __restrict__ Aroot,
                        const uint16_t* __restrict__ Broot,
                        const float* __restrict__ bq,
                        const float* __restrict__ bk,
                        const float* __restrict__ bv,
                        void* __restrict__ out0,
                        uint16_t* __restrict__ out1,
                        uint16_t* __restrict__ out2) {
  constexpr int K   = (MODE == 3) ? 2048 : 1024;
  constexpr int LDA = (MODE == 3) ? 2048 : 1024;
  constexpr int LDB = (MODE == 3) ? 2048 : 1024;

  const int tm = blockIdx.x, tn = blockIdx.y;
  if constexpr (MODE == 2) { if (tn > tm) return; }

  const uint16_t* A = Aroot;
  const uint16_t* Bp = Broot;
  uint16_t* C16 = (uint16_t*)out0;
  float*    C32 = (float*)out0;
  if constexpr (MODE == 2) {
    size_t z = blockIdx.z;
    A  += z * (size_t)(SS * DD);
    Bp += z * (size_t)(SS * DD);
    C16 += z * (size_t)SS * (size_t)SS;
  }
  if constexpr (MODE == 3) {
    size_t z = blockIdx.z;
    A  += z * (size_t)SS * (size_t)SS;
    Bp += z * (size_t)(HH * SS);
    C32 += z * (size_t)(SS * HH);
  }

  const int m0 = tm * 128, n0 = tn * 128;
  int kmax = K;
  if constexpr (MODE == 3) {
    kmax = (tm + 1) * 128;           // multiple of 128 -> multiple of 64
    if (kmax > K) kmax = K;
  }

  __shared__ uint16_t As0[128 * 32];
  __shared__ uint16_t As1[128 * 32];
  __shared__ uint16_t Bs0[128 * 32];
  __shared__ uint16_t Bs1[128 * 32];

  const int tid  = threadIdx.x;
  const int lane = tid & 63;
  const int wv   = tid >> 6;
  const int wm   = (wv & 1) * 64;   // wave's m offset within 128-tile
  const int wn   = (wv >> 1) * 64;  // wave's n offset

  f32x4 acc[4][4];
#pragma unroll
  for (int i = 0; i < 4; i++)
#pragma unroll
    for (int j = 0; j < 4; j++)
#pragma unroll
      for (int e = 0; e < 4; e++) acc[i][j][e] = 0.f;

  // global_load_lds lane mapping within a 16-row chunk:
  // lane l -> row l>>2, elem col (l&3)*8 (16B)
  const int lrow = lane >> 2;
  const int lcol = (lane & 3) * 8;
  const int r0   = wv * 32;         // this wave's 32-row slab

  const uint16_t* gA = A + (size_t)(m0 + r0 + lrow) * LDA + lcol;
  const uint16_t* gB = Bp + (size_t)(n0 + r0 + lrow) * LDB + lcol;

  // fragment indices (A and B operands share the same lane mapping)
  const int fr = lane & 15;
  const int fk = (lane >> 4) * 8;

  for (int k0 = 0; k0 < kmax; k0 += 64) {
    __syncthreads();  // prior ds_reads done before overwrite
    __builtin_amdgcn_global_load_lds(AS1C(gA + k0), AS3(&As0[r0 * 32]), 16, 0, 0);
    __builtin_amdgcn_global_load_lds(AS1C(gA + k0 + 16 * LDA), AS3(&As0[(r0 + 16) * 32]), 16, 0, 0);
    __builtin_amdgcn_global_load_lds(AS1C(gA + k0 + 32), AS3(&As1[r0 * 32]), 16, 0, 0);
    __builtin_amdgcn_global_load_lds(AS1C(gA + k0 + 32 + 16 * LDA), AS3(&As1[(r0 + 16) * 32]), 16, 0, 0);
    __builtin_amdgcn_global_load_lds(AS1C(gB + k0), AS3(&Bs0[r0 * 32]), 16, 0, 0);
    __builtin_amdgcn_global_load_lds(AS1C(gB + k0 + 16 * LDB), AS3(&Bs0[(r0 + 16) * 32]), 16, 0, 0);
    __builtin_amdgcn_global_load_lds(AS1C(gB + k0 + 32), AS3(&Bs1[r0 * 32]), 16, 0, 0);
    __builtin_amdgcn_global_load_lds(AS1C(gB + k0 + 32 + 16 * LDB), AS3(&Bs1[(r0 + 16) * 32]), 16, 0, 0);
    __syncthreads();  // drains vmcnt(0): both 32-chunks staged

    bf16x8 af[4], bfr[4];
#pragma unroll
    for (int i = 0; i < 4; i++)
      af[i] = __builtin_bit_cast(bf16x8, *(const uint4*)&As0[(wm + i * 16 + fr) * 32 + fk]);
#pragma unroll
    for (int j = 0; j < 4; j++)
      bfr[j] = __builtin_bit_cast(bf16x8, *(const uint4*)&Bs0[(wn + j * 16 + fr) * 32 + fk]);
#pragma unroll
    for (int i = 0; i < 4; i++)
#pragma unroll
      for (int j = 0; j < 4; j++)
        acc[i][j] = __builtin_amdgcn_mfma_f32_16x16x32_bf16(af[i], bfr[j], acc[i][j], 0, 0, 0);

#pragma unroll
    for (int i = 0; i < 4; i++)
      af[i] = __builtin_bit_cast(bf16x8, *(const uint4*)&As1[(wm + i * 16 + fr) * 32 + fk]);
#pragma unroll
    for (int j = 0; j < 4; j++)
      bfr[j] = __builtin_bit_cast(bf16x8, *(const uint4*)&Bs1[(wn + j * 16 + fr) * 32 + fk]);
#pragma unroll
    for (int i = 0; i < 4; i++)
#pragma unroll
      for (int j = 0; j < 4; j++)
        acc[i][j] = __builtin_amdgcn_mfma_f32_16x16x32_bf16(af[i], bfr[j], acc[i][j], 0, 0, 0);
  }

  // epilogue: C/D mapping col = lane&15, row = (lane>>4)*4 + e  [verified m89/m91]
  const int cr = (lane >> 4) * 4;
  const int cc = lane & 15;

  if constexpr (MODE == 0) {
    const int sel   = n0 >> 10;            // 0=Q, 1=K, 2=V (block-uniform)
    const int nloc0 = n0 & 1023;
    const float* __restrict__ bsel = (sel == 0) ? bq : (sel == 1) ? bk : bv;
    uint16_t* __restrict__ oQK = (sel == 1) ? out1 : (uint16_t*)out0;
#pragma unroll
    for (int i = 0; i < 4; i++) {
#pragma unroll
      for (int j = 0; j < 4; j++) {
        const int row0 = m0 + wm + i * 16 + cr;
        const int coll = nloc0 + wn + j * 16 + cc;
        const float badd = bsel[coll];
#pragma unroll
        for (int e = 0; e < 4; e++) {
          const float x = acc[i][j][e] + badd;
          const int r = row0 + e;
          if (sel == 2) {
            const int bz = r >> 11;
            const int s  = r & (SS - 1);
            out2[(size_t)bz * (HH * SS) + (size_t)coll * SS + s] = f2bf(x);
          } else {
            oQK[(size_t)r * HH + coll] = f2bf(x);
          }
        }
      }
    }
  } else {
#pragma unroll
    for (int i = 0; i < 4; i++) {
#pragma unroll
      for (int j = 0; j < 4; j++) {
        const int row0 = m0 + wm + i * 16 + cr;
        const int col  = n0 + wn + j * 16 + cc;
#pragma unroll
        for (int e = 0; e < 4; e++) {
          float x = acc[i][j][e];
          const int r = row0 + e;
          if constexpr (MODE == 2) {
            C16[(size_t)r * SS + col] = f2bf(x * 0.03125f);  // 1/sqrt(1024)
          } else {
            C32[(size_t)r * HH + col] = x;                   // fp32 final out
          }
        }
      }
    }
  }
}

// one block (256 threads) per row; each thread owns 8 contiguous columns.
// Reads S row (bf16), writes normalized P in-place, zero-fills j>i.
__launch_bounds__(256)
__global__ void softmax_causal(uint16_t* __restrict__ Sb) {
  const int rgl = blockIdx.x;          // 0..B*S-1
  const int b = rgl >> 11;
  const int i = rgl & (SS - 1);
  uint16_t* row = Sb + (size_t)b * SS * SS + (size_t)i * SS;
  const int t = threadIdx.x;
  const int base = t * 8;

  uint4 u = *(const uint4*)(row + base);
  const uint16_t* hs = (const uint16_t*)&u;
  float x[8];
  float lmax = -3.0e38f;
#pragma unroll
  for (int e = 0; e < 8; e++) {
    float f = bf2f(hs[e]);
    x[e] = (base + e <= i) ? f : -3.0e38f;
    lmax = fmaxf(lmax, x[e]);
  }
#pragma unroll
  for (int off = 32; off > 0; off >>= 1)
    lmax = fmaxf(lmax, __shfl_down(lmax, off));

  __shared__ float red[8];
  if ((t & 63) == 0) red[t >> 6] = lmax;
  __syncthreads();
  const float m = fmaxf(fmaxf(red[0], red[1]), fmaxf(red[2], red[3]));

  float lsum = 0.f;
#pragma unroll
  for (int e = 0; e < 8; e++) {
    float p = (base + e <= i) ? __expf(x[e] - m) : 0.f;
    x[e] = p;
    lsum += p;
  }
#pragma unroll
  for (int off = 32; off > 0; off >>= 1) lsum += __shfl_down(lsum, off);
  if ((t & 63) == 0) red[4 + (t >> 6)] = lsum;
  __syncthreads();
  const float inv = 1.f / (red[4] + red[5] + red[6] + red[7]);

  alignas(16) uint16_t o[8];
#pragma unroll
  for (int e = 0; e < 8; e++) o[e] = f2bf(x[e] * inv);
  *(uint4*)(row + base) = *(const uint4*)o;
}

extern "C" void kernel_launch(void* const* d_in, const int* in_sizes, int n_in,
                              void* d_out, int out_size, void* d_ws, size_t ws_size,
                              hipStream_t stream) {
  // Inputs fp32 per the reference; output fp32 (reference output dtype).
  const float* x  = (const float*)d_in[0];
  const float* Wq = (const float*)d_in[1];
  const float* bq = (const float*)d_in[2];
  const float* Wk = (const float*)d_in[3];
  const float* bk = (const float*)d_in[4];
  const float* Wv = (const float*)d_in[5];
  const float* bv = (const float*)d_in[6];

  uint16_t* ws = (uint16_t*)d_ws;
  const size_t QKV = (size_t)BB * SS * HH;  // 16,777,216 elems = 32 MB bf16
  uint16_t* Q  = ws;
  uint16_t* Kp = ws + QKV;
  uint16_t* Vt = ws + 2 * QKV;
  uint16_t* Sb = ws + 3 * QKV;              // 8*2048*2048 bf16 = 64 MB
  // xb + converted weights alias the Sb region (dead before MODE 2 writes Sb)
  uint16_t* xb  = Sb;                       // 16,777,216 elems
  uint16_t* Wqb = Sb + QKV;                 // Wq;Wk;Wv contiguous = Wcat 3072x1024
  uint16_t* Wkb = Wqb + (size_t)HH * DD;
  uint16_t* Wvb = Wkb + (size_t)HH * DD;

  dim3 blk(256);
  const int nx = BB * SS * DD;              // 16,777,216
  const int nw = HH * DD;                   // 1,048,576
  cvt_f32_bf16<<<dim3(nx / 2048), blk, 0, stream>>>(x, xb, nx);
  cvt3_f32_bf16<<<dim3(nw / 2048, 3), blk, 0, stream>>>(Wq, Wk, Wv, Wqb, Wkb, Wvb, nw);

  // merged QKV projection: N = 3072
  gemm_bt<0><<<dim3(BB * SS / 128, 3 * HH / 128), blk, 0, stream>>>(
      xb, Wqb, bq, bk, bv, Q, Kp, Vt);
  gemm_bt<2><<<dim3(SS / 128, SS / 128, BB), blk, 0, stream>>>(
      Q, Kp, nullptr, nullptr, nullptr, Sb, nullptr, nullptr);
  softmax_causal<<<dim3(BB * SS), blk, 0, stream>>>(Sb);
  gemm_bt<3><<<dim3(SS / 128, HH / 128, BB), blk, 0, stream>>>(
      Sb, Vt, nullptr, nullptr, nullptr, d_out, nullptr, nullptr);
}